// Round 9
// baseline (640.665 us; speedup 1.0000x reference)
//
#include <hip/hip_runtime.h>

#define NN 50000
#define NE 1000000

constexpr float LN_EPS = 1e-5f;

typedef short bf16x8 __attribute__((ext_vector_type(8)));
typedef float f32x4 __attribute__((ext_vector_type(4)));
typedef uint uvec4 __attribute__((ext_vector_type(4)));
typedef uint uvec2 __attribute__((ext_vector_type(2)));

// hardware RNE f32x2 -> bf16x2 pack (gfx950 v_cvt_pk_bf16_f32; no builtin)
__device__ inline uint cvtpk(float a, float b) {
  uint r;
  asm("v_cvt_pk_bf16_f32 %0, %1, %2" : "=v"(r) : "v"(a), "v"(b));
  return r;
}
__device__ inline ushort cvt1(float a) {
  uint r;
  asm("v_cvt_pk_bf16_f32 %0, %1, %1" : "=v"(r) : "v"(a));
  return (ushort)r;
}
__device__ inline float bflo(uint u) { union { uint x; float f; } v; v.x = u << 16; return v.f; }
__device__ inline float bfhi(uint u) { union { uint x; float f; } v; v.x = u & 0xffff0000u; return v.f; }

// ---------------------------------------------------------------------------
// CSR build: histogram -> exclusive scan -> scatter.
__global__ __launch_bounds__(256) void hist_kernel(const int* __restrict__ ei,
                                                   int* __restrict__ cnt) {
  int e = blockIdx.x * 256 + threadIdx.x;
  if (e < NE) atomicAdd(&cnt[ei[NE + e]], 1);
}

__global__ __launch_bounds__(256) void scan1_kernel(const int* __restrict__ cnt,
                                                    int* __restrict__ off,
                                                    int* __restrict__ bsum) {
  __shared__ int sh[256];
  int t = threadIdx.x;
  int idx = blockIdx.x * 256 + t;
  int v = (idx < NN) ? cnt[idx] : 0;
  sh[t] = v;
  __syncthreads();
  for (int o = 1; o < 256; o <<= 1) {
    int xv = (t >= o) ? sh[t - o] : 0;
    __syncthreads();
    sh[t] += xv;
    __syncthreads();
  }
  if (idx <= NN) off[idx] = sh[t] - v;
  if (t == 255) bsum[blockIdx.x] = sh[255];
}

__global__ __launch_bounds__(256) void scan2_kernel(int* __restrict__ bsum, int nb) {
  __shared__ int sh[256];
  int t = threadIdx.x;
  int v = (t < nb) ? bsum[t] : 0;
  sh[t] = v;
  __syncthreads();
  for (int o = 1; o < 256; o <<= 1) {
    int xv = (t >= o) ? sh[t - o] : 0;
    __syncthreads();
    sh[t] += xv;
    __syncthreads();
  }
  if (t < nb) bsum[t] = sh[t] - v;
}

__global__ __launch_bounds__(256) void scan3_kernel(int* __restrict__ off,
                                                    const int* __restrict__ bsum,
                                                    int* __restrict__ cnt) {
  int idx = blockIdx.x * 256 + threadIdx.x;
  if (idx <= NN) off[idx] += bsum[blockIdx.x];
  if (idx < NN) cnt[idx] = 0;
}

// scatter emits: srcp/dstp (sorted endpoint ids), eapb (dst-sorted bf16 edge
// attrs), ipos (edge -> sorted position inverse map, coalesced by e).
__global__ __launch_bounds__(256) void scatter_kernel(
    const int* __restrict__ ei, const float* __restrict__ ea,
    const int* __restrict__ off, int* __restrict__ cur,
    int* __restrict__ ipos, int* __restrict__ srcp, int* __restrict__ dstp,
    ushort* __restrict__ eapb) {
  int e = blockIdx.x * 256 + threadIdx.x;
  if (e < NE) {
    int d = ei[NE + e];
    int s = ei[e];
    int p = off[d] + atomicAdd(&cur[d], 1);
    ipos[e] = p;
    srcp[p] = s;
    dstp[p] = d;
    const float* eaf = ea + (size_t)e * 8;
    f32x4 e0 = *(const f32x4*)(eaf);
    f32x4 e1 = *(const f32x4*)(eaf + 4);
    uvec4 u;
    u.x = cvtpk(e0.x, e0.y);
    u.y = cvtpk(e0.z, e0.w);
    u.z = cvtpk(e1.x, e1.y);
    u.w = cvtpk(e1.z, e1.w);
    __builtin_nontemporal_store(u, (uvec4*)(eapb + (size_t)p * 8));
  }
}

// unpermute: coalesced write of out, random 4B read of the 4MB tmp table
// (L2-absorbed; random READS are cheap, random writes are not -- R8 lesson).
__global__ __launch_bounds__(256) void unperm_kernel(const float* __restrict__ tmp,
                                                     const int* __restrict__ ipos,
                                                     float* __restrict__ out) {
  int e = blockIdx.x * 256 + threadIdx.x;
  if (e < NE) out[e] = tmp[ipos[e]];
}

// ---------------------------------------------------------------------------
// Layer-0 aggregation (D=16): per-node wave, 4 edges in flight (slot = j>>4),
// writes the f32 16-dim aggregate only. MLP+residual+LN run in mlp0_kernel.
__global__ __launch_bounds__(256) void aggr0_kernel(
    const float* __restrict__ x, float* __restrict__ tout16,
    const ushort* __restrict__ eapb, const int* __restrict__ srcp,
    const int* __restrict__ off,
    const float* __restrict__ lw, const float* __restrict__ lb) {
  int n = blockIdx.x * 4 + (threadIdx.x >> 6);
  int j = threadIdx.x & 63;
  int d = j & 15, slot = j >> 4;
  int start = off[n], end = off[n + 1];
  float lwv[8];
#pragma unroll
  for (int i = 0; i < 8; i++) lwv[i] = lw[i * 16 + d];
  float lbv = lb[d];
  float acc = 0.f;
  for (int base = start; base < end; base += 64) {
    int idx = base + j;
    int sl = (idx < end) ? srcp[idx] : 0;
    int c = min(end - base, 64);
    for (int i0 = 0; i0 < c; i0 += 4) {
      int i = i0 + slot;
      bool valid = i < c;
      int ii = i & 63;
      int s = __shfl(sl, ii);
      int pp = min(base + i0 + slot, NE - 1);
      float ev = bflo((uint)eapb[(size_t)pp * 8 + (d & 7)]);
      float xs = x[(size_t)s * 16 + d];
      float m = lbv + xs;
#pragma unroll
      for (int q = 0; q < 8; q++) m = fmaf(__shfl(ev, slot * 16 + q), lwv[q], m);
      m = fmaxf(m, 0.f);
      acc += valid ? m : 0.f;
    }
  }
  acc += __shfl_xor(acc, 16);
  acc += __shfl_xor(acc, 32);
  if (slot == 0) tout16[(size_t)n * 16 + d] = acc;
}

// ---------------------------------------------------------------------------
// Aggregation for layers 1/2 (D=64): shfl-free edge loop (wave-uniform src
// ids + edge attrs via readfirstlane -> SGPR operands), 8 gathers in flight.
__device__ inline float edge8_msg(const ushort* __restrict__ hinb, int s, int j,
                                  uint ulo, uint uhi, uint vlo, uint vhi,
                                  const float* lwv, float lbv) {
  float hc = bflo((uint)hinb[(size_t)s * 64 + j]);
  float m = lbv + hc;
  m = fmaf(bflo(ulo), lwv[0], m);
  m = fmaf(bfhi(ulo), lwv[1], m);
  m = fmaf(bflo(uhi), lwv[2], m);
  m = fmaf(bfhi(uhi), lwv[3], m);
  m = fmaf(bflo(vlo), lwv[4], m);
  m = fmaf(bfhi(vlo), lwv[5], m);
  m = fmaf(bflo(vhi), lwv[6], m);
  m = fmaf(bfhi(vhi), lwv[7], m);
  return fmaxf(m, 0.f);
}

__global__ __launch_bounds__(256) void aggr_kernel(
    const ushort* __restrict__ hinb, float* __restrict__ tout,
    const ushort* __restrict__ eapb, const int* __restrict__ srcp,
    const int* __restrict__ off,
    const float* __restrict__ lw, const float* __restrict__ lb) {
  int n = blockIdx.x * 4 + (threadIdx.x >> 6);
  int j = threadIdx.x & 63;
  int start = __builtin_amdgcn_readfirstlane(off[n]);
  int end = __builtin_amdgcn_readfirstlane(off[n + 1]);
  float lwv[8];
#pragma unroll
  for (int i = 0; i < 8; i++) lwv[i] = lw[i * 64 + j];
  float lbv = lb[j];
  float acc = 0.f;
  int p = start;
  for (; p + 8 <= end; p += 8) {
    const uvec4* ip = (const uvec4*)(srcp + p);
    uvec4 I0 = __builtin_nontemporal_load(ip + 0);
    uvec4 I1 = __builtin_nontemporal_load(ip + 1);
    int s0 = __builtin_amdgcn_readfirstlane((int)I0.x);
    int s1 = __builtin_amdgcn_readfirstlane((int)I0.y);
    int s2 = __builtin_amdgcn_readfirstlane((int)I0.z);
    int s3 = __builtin_amdgcn_readfirstlane((int)I0.w);
    int s4 = __builtin_amdgcn_readfirstlane((int)I1.x);
    int s5 = __builtin_amdgcn_readfirstlane((int)I1.y);
    int s6 = __builtin_amdgcn_readfirstlane((int)I1.z);
    int s7 = __builtin_amdgcn_readfirstlane((int)I1.w);
    const uvec4* ep = (const uvec4*)(eapb + (size_t)p * 8);
    uint ua[8][4];
#pragma unroll
    for (int i = 0; i < 8; i++) {
      uvec4 E = __builtin_nontemporal_load(ep + i);
      ua[i][0] = __builtin_amdgcn_readfirstlane(E.x);
      ua[i][1] = __builtin_amdgcn_readfirstlane(E.y);
      ua[i][2] = __builtin_amdgcn_readfirstlane(E.z);
      ua[i][3] = __builtin_amdgcn_readfirstlane(E.w);
    }
    acc += edge8_msg(hinb, s0, j, ua[0][0], ua[0][1], ua[0][2], ua[0][3], lwv, lbv);
    acc += edge8_msg(hinb, s1, j, ua[1][0], ua[1][1], ua[1][2], ua[1][3], lwv, lbv);
    acc += edge8_msg(hinb, s2, j, ua[2][0], ua[2][1], ua[2][2], ua[2][3], lwv, lbv);
    acc += edge8_msg(hinb, s3, j, ua[3][0], ua[3][1], ua[3][2], ua[3][3], lwv, lbv);
    acc += edge8_msg(hinb, s4, j, ua[4][0], ua[4][1], ua[4][2], ua[4][3], lwv, lbv);
    acc += edge8_msg(hinb, s5, j, ua[5][0], ua[5][1], ua[5][2], ua[5][3], lwv, lbv);
    acc += edge8_msg(hinb, s6, j, ua[6][0], ua[6][1], ua[6][2], ua[6][3], lwv, lbv);
    acc += edge8_msg(hinb, s7, j, ua[7][0], ua[7][1], ua[7][2], ua[7][3], lwv, lbv);
  }
  for (; p < end; p++) {
    int s = __builtin_amdgcn_readfirstlane(srcp[p]);
    uvec4 E = __builtin_nontemporal_load((const uvec4*)(eapb + (size_t)p * 8));
    uint e0 = __builtin_amdgcn_readfirstlane(E.x);
    uint e1 = __builtin_amdgcn_readfirstlane(E.y);
    uint e2 = __builtin_amdgcn_readfirstlane(E.z);
    uint e3 = __builtin_amdgcn_readfirstlane(E.w);
    acc += edge8_msg(hinb, s, j, e0, e1, e2, e3, lwv, lbv);
  }
  tout[(size_t)n * 64 + j] = acc;
}

// ---------------------------------------------------------------------------
// Prep: dec_w1 (264x64, K zero-padded to 288) and dec_w2 (64x32) into per-lane
// bf16 B-fragments for mfma_f32_16x16x32_bf16.
__global__ __launch_bounds__(256) void prep_kernel(
    const float* __restrict__ w1, const float* __restrict__ w2,
    ushort* __restrict__ w1f, ushort* __restrict__ w2f) {
  int t = blockIdx.x * 256 + threadIdx.x;
  if (t < 18432) {
    int j = t & 7, lane = (t >> 3) & 63, f = t >> 9;
    int k = (f >> 2) * 32 + ((lane >> 4) * 8) + j;
    int n = (f & 3) * 16 + (lane & 15);
    float v = (k < 264) ? w1[k * 64 + n] : 0.f;
    w1f[t] = cvt1(v);
  } else {
    int t2 = t - 18432;
    int j = t2 & 7, lane = (t2 >> 3) & 63, f = t2 >> 9;
    int k = (f >> 1) * 32 + ((lane >> 4) * 8) + j;
    int n = (f & 1) * 16 + (lane & 15);
    w2f[t2] = cvt1(w2[k * 32 + n]);
  }
}

// Prep hi/lo B-fragments for the layer-1/2 MLP weights (each 64x64).
// Output layout per layer (16384 ushorts): [w1h, w1l, w2h, w2l] x 4096.
__global__ __launch_bounds__(256) void prep_mlpw(
    const float* __restrict__ w1a, const float* __restrict__ w2a,
    const float* __restrict__ w1b, const float* __restrict__ w2b,
    ushort* __restrict__ out) {
  int t = blockIdx.x * 256 + threadIdx.x;  // 16384 threads
  int layer = t >> 13, wsel = (t >> 12) & 1, idx = t & 4095;
  const float* w = layer ? (wsel ? w2b : w1b) : (wsel ? w2a : w1a);
  int j = idx & 7, lane = (idx >> 3) & 63, f = idx >> 9;
  int k = (f >> 2) * 32 + ((lane >> 4) * 8) + j;
  int n = (f & 3) * 16 + (lane & 15);
  float v = w[k * 64 + n];
  ushort h = cvt1(v);
  float r = v - bflo((uint)h);
  ushort lo = cvt1(r);
  int base = layer * 16384 + wsel * 8192;
  out[base + idx] = h;
  out[base + 4096 + idx] = lo;
}

// Prep layer-0 MLP B-fragments (hi/lo): B1 = [w1(16x64); 0] (K=32, 4 frags),
// B2 = [0; rw(16x64)] (4 frags), W2 = w2(64x64) (8 frags).
// Layout: [B1h 0][B1l 2048][B2h 4096][B2l 6144][W2h 8192][W2l 12288].
__global__ __launch_bounds__(256) void prep_mlp0(
    const float* __restrict__ w1, const float* __restrict__ w2,
    const float* __restrict__ rw, ushort* __restrict__ out) {
  int t = blockIdx.x * 256 + threadIdx.x;  // 8192 threads
  if (t < 4096) {
    int which = t >> 11, idx = t & 2047;
    int j = idx & 7, lane = (idx >> 3) & 63, f = idx >> 9;
    int k = ((lane >> 4) * 8) + j;
    int n = f * 16 + (lane & 15);
    float v;
    if (which == 0) v = (k < 16) ? w1[k * 64 + n] : 0.f;
    else            v = (k >= 16) ? rw[(k - 16) * 64 + n] : 0.f;
    ushort h = cvt1(v);
    float r = v - bflo((uint)h);
    int base = which * 4096;
    out[base + idx] = h;
    out[base + 2048 + idx] = cvt1(r);
  } else {
    int idx = t - 4096;  // 0..4095
    int j = idx & 7, lane = (idx >> 3) & 63, f = idx >> 9;
    int k = (f >> 2) * 32 + ((lane >> 4) * 8) + j;
    int n = (f & 3) * 16 + (lane & 15);
    float v = w2[k * 64 + n];
    ushort h = cvt1(v);
    float r = v - bflo((uint)h);
    out[8192 + idx] = h;
    out[12288 + idx] = cvt1(r);
  }
}

// ---------------------------------------------------------------------------
// MFMA node-MLP + LayerNorm for layers 1/2. M=32 rows per wave, 2 waves/block.
#define YS2 68

__global__ __launch_bounds__(128) void mlp_kernel(
    const float* __restrict__ tacc, const float* __restrict__ hinf,
    float* __restrict__ houtf, ushort* __restrict__ houtbf,
    const ushort* __restrict__ wf,
    const float* __restrict__ b1, const float* __restrict__ b2,
    const float* __restrict__ lng, const float* __restrict__ lnb) {
  __shared__ float ybuf[2][32 * YS2];
  const int w = threadIdx.x >> 6, l = threadIdx.x & 63;
  const int sub = l & 15, quad = l >> 4;
  const int wid = blockIdx.x * 2 + w;
  const int r0 = wid * 32;
  if (r0 >= NN) return;
  float* Y = ybuf[w];

  const bf16x8* w1h = (const bf16x8*)wf;
  const bf16x8* w1l = (const bf16x8*)(wf + 4096);
  const bf16x8* w2h = (const bf16x8*)(wf + 8192);
  const bf16x8* w2l = (const bf16x8*)(wf + 12288);

  union UF { uvec4 u; bf16x8 v; };

  // stage-1 A fragments (hi/lo) from t = tacc + hinf
  bf16x8 Ahi[2][2], Alo[2][2];
#pragma unroll
  for (int m = 0; m < 2; m++) {
    int row = min(r0 + m * 16 + sub, NN - 1);
    const float* pt = tacc + (size_t)row * 64 + quad * 8;
    const float* ph = hinf + (size_t)row * 64 + quad * 8;
#pragma unroll
    for (int ks = 0; ks < 2; ks++) {
      f32x4 t0 = *(const f32x4*)(pt + ks * 32);
      f32x4 t1 = *(const f32x4*)(pt + ks * 32 + 4);
      f32x4 h0 = *(const f32x4*)(ph + ks * 32);
      f32x4 h1 = *(const f32x4*)(ph + ks * 32 + 4);
      t0 += h0;
      t1 += h1;
      UF uh, ul;
      uh.u.x = cvtpk(t0.x, t0.y);
      uh.u.y = cvtpk(t0.z, t0.w);
      uh.u.z = cvtpk(t1.x, t1.y);
      uh.u.w = cvtpk(t1.z, t1.w);
      ul.u.x = cvtpk(t0.x - bflo(uh.u.x), t0.y - bfhi(uh.u.x));
      ul.u.y = cvtpk(t0.z - bflo(uh.u.y), t0.w - bfhi(uh.u.y));
      ul.u.z = cvtpk(t1.x - bflo(uh.u.z), t1.y - bfhi(uh.u.z));
      ul.u.w = cvtpk(t1.z - bflo(uh.u.w), t1.w - bfhi(uh.u.w));
      Ahi[m][ks] = uh.v;
      Alo[m][ks] = ul.v;
    }
  }

  f32x4 c1[2][4];
#pragma unroll
  for (int m = 0; m < 2; m++)
#pragma unroll
    for (int nb = 0; nb < 4; nb++) c1[m][nb] = (f32x4){0.f, 0.f, 0.f, 0.f};
#pragma unroll
  for (int nb = 0; nb < 4; nb++) {
#pragma unroll
    for (int ks = 0; ks < 2; ks++) {
      bf16x8 bh = w1h[(ks * 4 + nb) * 64 + l];
      bf16x8 bl = w1l[(ks * 4 + nb) * 64 + l];
      c1[0][nb] = __builtin_amdgcn_mfma_f32_16x16x32_bf16(Ahi[0][ks], bh, c1[0][nb], 0, 0, 0);
      c1[1][nb] = __builtin_amdgcn_mfma_f32_16x16x32_bf16(Ahi[1][ks], bh, c1[1][nb], 0, 0, 0);
      c1[0][nb] = __builtin_amdgcn_mfma_f32_16x16x32_bf16(Alo[0][ks], bh, c1[0][nb], 0, 0, 0);
      c1[1][nb] = __builtin_amdgcn_mfma_f32_16x16x32_bf16(Alo[1][ks], bh, c1[1][nb], 0, 0, 0);
      c1[0][nb] = __builtin_amdgcn_mfma_f32_16x16x32_bf16(Ahi[0][ks], bl, c1[0][nb], 0, 0, 0);
      c1[1][nb] = __builtin_amdgcn_mfma_f32_16x16x32_bf16(Ahi[1][ks], bl, c1[1][nb], 0, 0, 0);
    }
  }

  float b1v[4];
#pragma unroll
  for (int nb = 0; nb < 4; nb++) b1v[nb] = b1[nb * 16 + sub];
#pragma unroll
  for (int m = 0; m < 2; m++)
#pragma unroll
    for (int nb = 0; nb < 4; nb++)
#pragma unroll
      for (int r = 0; r < 4; r++)
        Y[(m * 16 + quad * 4 + r) * YS2 + nb * 16 + sub] =
            fmaxf(c1[m][nb][r] + b1v[nb], 0.f);

  bf16x8 Qhi[2][2], Qlo[2][2];
#pragma unroll
  for (int m = 0; m < 2; m++) {
#pragma unroll
    for (int ks = 0; ks < 2; ks++) {
      const float* py = &Y[(m * 16 + sub) * YS2 + ks * 32 + quad * 8];
      f32x4 q0 = *(const f32x4*)py;
      f32x4 q1 = *(const f32x4*)(py + 4);
      UF uh, ul;
      uh.u.x = cvtpk(q0.x, q0.y);
      uh.u.y = cvtpk(q0.z, q0.w);
      uh.u.z = cvtpk(q1.x, q1.y);
      uh.u.w = cvtpk(q1.z, q1.w);
      ul.u.x = cvtpk(q0.x - bflo(uh.u.x), q0.y - bfhi(uh.u.x));
      ul.u.y = cvtpk(q0.z - bflo(uh.u.y), q0.w - bfhi(uh.u.y));
      ul.u.z = cvtpk(q1.x - bflo(uh.u.z), q1.y - bfhi(uh.u.z));
      ul.u.w = cvtpk(q1.z - bflo(uh.u.w), q1.w - bfhi(uh.u.w));
      Qhi[m][ks] = uh.v;
      Qlo[m][ks] = ul.v;
    }
  }

  f32x4 c2[2][4];
#pragma unroll
  for (int m = 0; m < 2; m++)
#pragma unroll
    for (int nb = 0; nb < 4; nb++) c2[m][nb] = (f32x4){0.f, 0.f, 0.f, 0.f};
#pragma unroll
  for (int nb = 0; nb < 4; nb++) {
#pragma unroll
    for (int ks = 0; ks < 2; ks++) {
      bf16x8 bh = w2h[(ks * 4 + nb) * 64 + l];
      bf16x8 bl = w2l[(ks * 4 + nb) * 64 + l];
      c2[0][nb] = __builtin_amdgcn_mfma_f32_16x16x32_bf16(Qhi[0][ks], bh, c2[0][nb], 0, 0, 0);
      c2[1][nb] = __builtin_amdgcn_mfma_f32_16x16x32_bf16(Qhi[1][ks], bh, c2[1][nb], 0, 0, 0);
      c2[0][nb] = __builtin_amdgcn_mfma_f32_16x16x32_bf16(Qlo[0][ks], bh, c2[0][nb], 0, 0, 0);
      c2[1][nb] = __builtin_amdgcn_mfma_f32_16x16x32_bf16(Qlo[1][ks], bh, c2[1][nb], 0, 0, 0);
      c2[0][nb] = __builtin_amdgcn_mfma_f32_16x16x32_bf16(Qhi[0][ks], bl, c2[0][nb], 0, 0, 0);
      c2[1][nb] = __builtin_amdgcn_mfma_f32_16x16x32_bf16(Qhi[1][ks], bl, c2[1][nb], 0, 0, 0);
    }
  }

  float b2v[4], lngv[4], lnbv[4];
#pragma unroll
  for (int nb = 0; nb < 4; nb++) {
    b2v[nb] = b2[nb * 16 + sub];
    lngv[nb] = lng[nb * 16 + sub];
    lnbv[nb] = lnb[nb * 16 + sub];
  }
#pragma unroll
  for (int m = 0; m < 2; m++) {
#pragma unroll
    for (int r = 0; r < 4; r++) {
      int node = r0 + m * 16 + quad * 4 + r;
      int nc = min(node, NN - 1);
      float vp[4];
      float s = 0.f;
#pragma unroll
      for (int nb = 0; nb < 4; nb++) {
        vp[nb] = fmaxf(c2[m][nb][r] + b2v[nb], 0.f) +
                 hinf[(size_t)nc * 64 + nb * 16 + sub];
        s += vp[nb];
      }
      s += __shfl_xor(s, 1);
      s += __shfl_xor(s, 2);
      s += __shfl_xor(s, 4);
      s += __shfl_xor(s, 8);
      float mu = s * (1.f / 64.f);
      float vv = 0.f;
      float dv[4];
#pragma unroll
      for (int nb = 0; nb < 4; nb++) {
        dv[nb] = vp[nb] - mu;
        vv += dv[nb] * dv[nb];
      }
      vv += __shfl_xor(vv, 1);
      vv += __shfl_xor(vv, 2);
      vv += __shfl_xor(vv, 4);
      vv += __shfl_xor(vv, 8);
      float rstd = rsqrtf(vv * (1.f / 64.f) + LN_EPS);
      if (node < NN) {
#pragma unroll
        for (int nb = 0; nb < 4; nb++) {
          float o = dv[nb] * rstd * lngv[nb] + lnbv[nb];
          if (houtf) houtf[(size_t)node * 64 + nb * 16 + sub] = o;
          houtbf[(size_t)node * 64 + nb * 16 + sub] = cvt1(o);
        }
      }
    }
  }
}

// ---------------------------------------------------------------------------
// MFMA node-MLP for layer 0. A = [t | x] (K=32, t = x + aggr16); stage 1
// computes q1 = relu(A@[w1;0]+b1) and res = A@[0;rw] (+rb in epilogue) in one
// fragment pass; stage 2 q1@w2; epilogue LN(relu(.)+res).
__global__ __launch_bounds__(128) void mlp0_kernel(
    const float* __restrict__ x, const float* __restrict__ tacc16,
    float* __restrict__ houtf, ushort* __restrict__ houtbf,
    const ushort* __restrict__ wf,
    const float* __restrict__ b1, const float* __restrict__ b2,
    const float* __restrict__ rb,
    const float* __restrict__ lng, const float* __restrict__ lnb) {
  __shared__ float ybuf[2][32 * YS2];
  const int w = threadIdx.x >> 6, l = threadIdx.x & 63;
  const int sub = l & 15, quad = l >> 4;
  const int wid = blockIdx.x * 2 + w;
  const int r0 = wid * 32;
  if (r0 >= NN) return;
  float* Y = ybuf[w];

  const bf16x8* B1h = (const bf16x8*)wf;
  const bf16x8* B1l = (const bf16x8*)(wf + 2048);
  const bf16x8* B2h = (const bf16x8*)(wf + 4096);
  const bf16x8* B2l = (const bf16x8*)(wf + 6144);
  const bf16x8* W2h = (const bf16x8*)(wf + 8192);
  const bf16x8* W2l = (const bf16x8*)(wf + 12288);

  union UF { uvec4 u; bf16x8 v; };

  // A_cat frags: quads 0,1 -> t = x+aggr (k=0..15); quads 2,3 -> x (k=16..31)
  bf16x8 Ahi[2], Alo[2];
#pragma unroll
  for (int m = 0; m < 2; m++) {
    int row = min(r0 + m * 16 + sub, NN - 1);
    const float* px = x + (size_t)row * 16 + (quad & 1) * 8;
    f32x4 v0 = *(const f32x4*)px;
    f32x4 v1 = *(const f32x4*)(px + 4);
    if (quad < 2) {
      const float* pt = tacc16 + (size_t)row * 16 + (quad & 1) * 8;
      v0 += *(const f32x4*)pt;
      v1 += *(const f32x4*)(pt + 4);
    }
    UF uh, ul;
    uh.u.x = cvtpk(v0.x, v0.y);
    uh.u.y = cvtpk(v0.z, v0.w);
    uh.u.z = cvtpk(v1.x, v1.y);
    uh.u.w = cvtpk(v1.z, v1.w);
    ul.u.x = cvtpk(v0.x - bflo(uh.u.x), v0.y - bfhi(uh.u.x));
    ul.u.y = cvtpk(v0.z - bflo(uh.u.y), v0.w - bfhi(uh.u.y));
    ul.u.z = cvtpk(v1.x - bflo(uh.u.z), v1.y - bfhi(uh.u.z));
    ul.u.w = cvtpk(v1.z - bflo(uh.u.w), v1.w - bfhi(uh.u.w));
    Ahi[m] = uh.v;
    Alo[m] = ul.v;
  }

  f32x4 c1[2][4], cr[2][4];
#pragma unroll
  for (int m = 0; m < 2; m++)
#pragma unroll
    for (int nb = 0; nb < 4; nb++) {
      c1[m][nb] = (f32x4){0.f, 0.f, 0.f, 0.f};
      cr[m][nb] = (f32x4){0.f, 0.f, 0.f, 0.f};
    }
#pragma unroll
  for (int nb = 0; nb < 4; nb++) {
    bf16x8 bh = B1h[nb * 64 + l];
    bf16x8 bl = B1l[nb * 64 + l];
    c1[0][nb] = __builtin_amdgcn_mfma_f32_16x16x32_bf16(Ahi[0], bh, c1[0][nb], 0, 0, 0);
    c1[1][nb] = __builtin_amdgcn_mfma_f32_16x16x32_bf16(Ahi[1], bh, c1[1][nb], 0, 0, 0);
    c1[0][nb] = __builtin_amdgcn_mfma_f32_16x16x32_bf16(Alo[0], bh, c1[0][nb], 0, 0, 0);
    c1[1][nb] = __builtin_amdgcn_mfma_f32_16x16x32_bf16(Alo[1], bh, c1[1][nb], 0, 0, 0);
    c1[0][nb] = __builtin_amdgcn_mfma_f32_16x16x32_bf16(Ahi[0], bl, c1[0][nb], 0, 0, 0);
    c1[1][nb] = __builtin_amdgcn_mfma_f32_16x16x32_bf16(Ahi[1], bl, c1[1][nb], 0, 0, 0);
    bf16x8 rh = B2h[nb * 64 + l];
    bf16x8 rl = B2l[nb * 64 + l];
    cr[0][nb] = __builtin_amdgcn_mfma_f32_16x16x32_bf16(Ahi[0], rh, cr[0][nb], 0, 0, 0);
    cr[1][nb] = __builtin_amdgcn_mfma_f32_16x16x32_bf16(Ahi[1], rh, cr[1][nb], 0, 0, 0);
    cr[0][nb] = __builtin_amdgcn_mfma_f32_16x16x32_bf16(Alo[0], rh, cr[0][nb], 0, 0, 0);
    cr[1][nb] = __builtin_amdgcn_mfma_f32_16x16x32_bf16(Alo[1], rh, cr[1][nb], 0, 0, 0);
    cr[0][nb] = __builtin_amdgcn_mfma_f32_16x16x32_bf16(Ahi[0], rl, cr[0][nb], 0, 0, 0);
    cr[1][nb] = __builtin_amdgcn_mfma_f32_16x16x32_bf16(Ahi[1], rl, cr[1][nb], 0, 0, 0);
  }

  float b1v[4];
#pragma unroll
  for (int nb = 0; nb < 4; nb++) b1v[nb] = b1[nb * 16 + sub];
#pragma unroll
  for (int m = 0; m < 2; m++)
#pragma unroll
    for (int nb = 0; nb < 4; nb++)
#pragma unroll
      for (int r = 0; r < 4; r++)
        Y[(m * 16 + quad * 4 + r) * YS2 + nb * 16 + sub] =
            fmaxf(c1[m][nb][r] + b1v[nb], 0.f);

  bf16x8 Qhi[2][2], Qlo[2][2];
#pragma unroll
  for (int m = 0; m < 2; m++) {
#pragma unroll
    for (int ks = 0; ks < 2; ks++) {
      const float* py = &Y[(m * 16 + sub) * YS2 + ks * 32 + quad * 8];
      f32x4 q0 = *(const f32x4*)py;
      f32x4 q1 = *(const f32x4*)(py + 4);
      UF uh, ul;
      uh.u.x = cvtpk(q0.x, q0.y);
      uh.u.y = cvtpk(q0.z, q0.w);
      uh.u.z = cvtpk(q1.x, q1.y);
      uh.u.w = cvtpk(q1.z, q1.w);
      ul.u.x = cvtpk(q0.x - bflo(uh.u.x), q0.y - bfhi(uh.u.x));
      ul.u.y = cvtpk(q0.z - bflo(uh.u.y), q0.w - bfhi(uh.u.y));
      ul.u.z = cvtpk(q1.x - bflo(uh.u.z), q1.y - bfhi(uh.u.z));
      ul.u.w = cvtpk(q1.z - bflo(uh.u.w), q1.w - bfhi(uh.u.w));
      Qhi[m][ks] = uh.v;
      Qlo[m][ks] = ul.v;
    }
  }

  f32x4 c2[2][4];
#pragma unroll
  for (int m = 0; m < 2; m++)
#pragma unroll
    for (int nb = 0; nb < 4; nb++) c2[m][nb] = (f32x4){0.f, 0.f, 0.f, 0.f};
#pragma unroll
  for (int nb = 0; nb < 4; nb++) {
#pragma unroll
    for (int ks = 0; ks < 2; ks++) {
      bf16x8 bh = W2h[(ks * 4 + nb) * 64 + l];
      bf16x8 bl = W2l[(ks * 4 + nb) * 64 + l];
      c2[0][nb] = __builtin_amdgcn_mfma_f32_16x16x32_bf16(Qhi[0][ks], bh, c2[0][nb], 0, 0, 0);
      c2[1][nb] = __builtin_amdgcn_mfma_f32_16x16x32_bf16(Qhi[1][ks], bh, c2[1][nb], 0, 0, 0);
      c2[0][nb] = __builtin_amdgcn_mfma_f32_16x16x32_bf16(Qlo[0][ks], bh, c2[0][nb], 0, 0, 0);
      c2[1][nb] = __builtin_amdgcn_mfma_f32_16x16x32_bf16(Qlo[1][ks], bh, c2[1][nb], 0, 0, 0);
      c2[0][nb] = __builtin_amdgcn_mfma_f32_16x16x32_bf16(Qhi[0][ks], bl, c2[0][nb], 0, 0, 0);
      c2[1][nb] = __builtin_amdgcn_mfma_f32_16x16x32_bf16(Qhi[1][ks], bl, c2[1][nb], 0, 0, 0);
    }
  }

  float b2v[4], rbv[4], lngv[4], lnbv[4];
#pragma unroll
  for (int nb = 0; nb < 4; nb++) {
    b2v[nb] = b2[nb * 16 + sub];
    rbv[nb] = rb[nb * 16 + sub];
    lngv[nb] = lng[nb * 16 + sub];
    lnbv[nb] = lnb[nb * 16 + sub];
  }
#pragma unroll
  for (int m = 0; m < 2; m++) {
#pragma unroll
    for (int r = 0; r < 4; r++) {
      int node = r0 + m * 16 + quad * 4 + r;
      float vp[4];
      float s = 0.f;
#pragma unroll
      for (int nb = 0; nb < 4; nb++) {
        vp[nb] = fmaxf(c2[m][nb][r] + b2v[nb], 0.f) + cr[m][nb][r] + rbv[nb];
        s += vp[nb];
      }
      s += __shfl_xor(s, 1);
      s += __shfl_xor(s, 2);
      s += __shfl_xor(s, 4);
      s += __shfl_xor(s, 8);
      float mu = s * (1.f / 64.f);
      float vv = 0.f;
      float dv[4];
#pragma unroll
      for (int nb = 0; nb < 4; nb++) {
        dv[nb] = vp[nb] - mu;
        vv += dv[nb] * dv[nb];
      }
      vv += __shfl_xor(vv, 1);
      vv += __shfl_xor(vv, 2);
      vv += __shfl_xor(vv, 4);
      vv += __shfl_xor(vv, 8);
      float rstd = rsqrtf(vv * (1.f / 64.f) + LN_EPS);
      if (node < NN) {
#pragma unroll
        for (int nb = 0; nb < 4; nb++) {
          float o = dv[nb] * rstd * lngv[nb] + lnbv[nb];
          houtf[(size_t)node * 64 + nb * 16 + sub] = o;
          houtbf[(size_t)node * 64 + nb * 16 + sub] = cvt1(o);
        }
      }
    }
  }
}

// ---------------------------------------------------------------------------
// MFMA decoder, CSR-ordered, M=32 per wave (R5-proven body). Each wave now
// processes 4 consecutive groups SEQUENTIALLY (#pragma unroll 1 -- must NOT
// unroll: unrolling hoists all gathers into registers and spills, the R6
// failure). Amortizes per-wave weight/bias setup and cuts grid 4x. tmp +
// unperm output path (random READS are L2-cheap; random writes are not).
#define YS 72
#define NGRP 31250
#define NTASK 7813
#define NBLKD 3907
#define BPXD 489

__device__ inline void absmul(bf16x8 a, bf16x8 b, bf16x8& dd, bf16x8& pp) {
  union U { bf16x8 v; uvec4 u; } ua, ub, ud, up;
  ua.v = a; ub.v = b;
#pragma unroll
  for (int i = 0; i < 4; i++) {
    float a0 = bflo(ua.u[i]), a1 = bfhi(ua.u[i]);
    float b0 = bflo(ub.u[i]), b1 = bfhi(ub.u[i]);
    ud.u[i] = cvtpk(fabsf(a0 - b0), fabsf(a1 - b1));
    up.u[i] = cvtpk(a0 * b0, a1 * b1);
  }
  dd = ud.v; pp = up.v;
}

__global__ __launch_bounds__(128, 4) void decoder_kernel(
    const ushort* __restrict__ hb,
    const int* __restrict__ srcp, const int* __restrict__ dstp,
    const ushort* __restrict__ eapb,
    const ushort* __restrict__ w1f, const ushort* __restrict__ w2f,
    const float* __restrict__ b1, const float* __restrict__ b2,
    const float* __restrict__ w3, const float* __restrict__ b3,
    float* __restrict__ tmp) {
  __shared__ ushort ybuf[2][32 * YS];
  const int w = threadIdx.x >> 6, l = threadIdx.x & 63;
  const int sub = l & 15, quad = l >> 4;
  int bb = (blockIdx.x & 7) * BPXD + (blockIdx.x >> 3);
  if (bb >= NBLKD) return;
  const int v = bb * 2 + w;
  if (v >= NTASK) return;
  ushort* Y = ybuf[w];

  // per-wave constants (amortized over the 4 groups)
  float b1v[4];
#pragma unroll
  for (int t = 0; t < 4; t++) b1v[t] = b1[t * 16 + sub];
  float b2v0 = b2[sub], b2v1 = b2[16 + sub];
  float w3v0 = w3[sub], w3v1 = w3[16 + sub];
  float b3v = b3[0];

#pragma unroll 1
  for (int q = 0; q < 4; q++) {
    const int g = v * 4 + q;
    if (g >= NGRP) break;

    int s32 = __builtin_nontemporal_load(&srcp[g * 32 + (l & 31)]);
    int d32 = __builtin_nontemporal_load(&dstp[g * 32 + (l & 31)]);

    bf16x8 alo[2], ahi[2], blo[2], bhi[2];
#pragma unroll
    for (int m = 0; m < 2; m++) {
      int sA = __shfl(s32, m * 16 + sub);
      int dA = __shfl(d32, m * 16 + sub);
      const ushort* pa = hb + (size_t)sA * 64 + quad * 8;
      const ushort* pb = hb + (size_t)dA * 64 + quad * 8;
      alo[m] = *(const bf16x8*)pa;
      ahi[m] = *(const bf16x8*)(pa + 32);
      blo[m] = *(const bf16x8*)pb;
      bhi[m] = *(const bf16x8*)(pb + 32);
    }
    bf16x8 eaf0 = (bf16x8){0, 0, 0, 0, 0, 0, 0, 0};
    bf16x8 eaf1 = (bf16x8){0, 0, 0, 0, 0, 0, 0, 0};
    if (quad == 0) {
      eaf0 = *(const bf16x8*)&eapb[((size_t)g * 32 + sub) * 8];
      eaf1 = *(const bf16x8*)&eapb[((size_t)g * 32 + 16 + sub) * 8];
    }

    f32x4 acc[2][4];
#pragma unroll
    for (int m = 0; m < 2; m++)
#pragma unroll
      for (int t = 0; t < 4; t++) acc[m][t] = (f32x4){0.f, 0.f, 0.f, 0.f};

#define MF(sB, f0, f1)                                                          \
    {                                                                           \
      _Pragma("unroll") for (int t = 0; t < 4; t++) {                           \
        bf16x8 bfv = ((const bf16x8*)w1f)[((sB)*4 + t) * 64 + l];               \
        acc[0][t] = __builtin_amdgcn_mfma_f32_16x16x32_bf16(f0, bfv, acc[0][t], \
                                                            0, 0, 0);           \
        acc[1][t] = __builtin_amdgcn_mfma_f32_16x16x32_bf16(f1, bfv, acc[1][t], \
                                                            0, 0, 0);           \
      }                                                                         \
    }

    {
      bf16x8 dlo0, plo0, dlo1, plo1;
      absmul(alo[0], blo[0], dlo0, plo0);
      absmul(alo[1], blo[1], dlo1, plo1);
      MF(0, alo[0], alo[1]);
      MF(2, blo[0], blo[1]);
      MF(4, dlo0, dlo1);
      MF(6, plo0, plo1);
    }
    {
      bf16x8 dhi0, phi0, dhi1, phi1;
      absmul(ahi[0], bhi[0], dhi0, phi0);
      absmul(ahi[1], bhi[1], dhi1, phi1);
      MF(1, ahi[0], ahi[1]);
      MF(3, bhi[0], bhi[1]);
      MF(5, dhi0, dhi1);
      MF(7, phi0, phi1);
    }
    MF(8, eaf0, eaf1);
#undef MF

#pragma unroll
    for (int m = 0; m < 2; m++)
#pragma unroll
      for (int t = 0; t < 4; t++)
#pragma unroll
        for (int r = 0; r < 4; r++)
          Y[(m * 16 + quad * 4 + r) * YS + t * 16 + sub] =
              cvt1(fmaxf(acc[m][t][r] + b1v[t], 0.f));

    bf16x8 w2frag[4];
#pragma unroll
    for (int f = 0; f < 4; f++) w2frag[f] = ((const bf16x8*)w2f)[f * 64 + l];
    f32x4 acc2[2][2];
#pragma unroll
    for (int m = 0; m < 2; m++) {
      acc2[m][0] = (f32x4){0.f, 0.f, 0.f, 0.f};
      acc2[m][1] = (f32x4){0.f, 0.f, 0.f, 0.f};
#pragma unroll
      for (int ks = 0; ks < 2; ks++) {
        bf16x8 ya = *(const bf16x8*)&Y[(m * 16 + sub) * YS + ks * 32 + quad * 8];
        acc2[m][0] = __builtin_amdgcn_mfma_f32_16x16x32_bf16(ya, w2frag[ks * 2 + 0],
                                                             acc2[m][0], 0, 0, 0);
        acc2[m][1] = __builtin_amdgcn_mfma_f32_16x16x32_bf16(ya, w2frag[ks * 2 + 1],
                                                             acc2[m][1], 0, 0, 0);
      }
    }
#pragma unroll
    for (int m = 0; m < 2; m++)
#pragma unroll
      for (int r = 0; r < 4; r++) {
        float o = fmaxf(acc2[m][0][r] + b2v0, 0.f) * w3v0 +
                  fmaxf(acc2[m][1][r] + b2v1, 0.f) * w3v1;
        o += __shfl_xor(o, 1);
        o += __shfl_xor(o, 2);
        o += __shfl_xor(o, 4);
        o += __shfl_xor(o, 8);
        if (sub == 0) tmp[g * 32 + m * 16 + quad * 4 + r] = o + b3v;
      }
  }
}

// ---------------------------------------------------------------------------
extern "C" void kernel_launch(void* const* d_in, const int* in_sizes, int n_in,
                              void* d_out, int out_size, void* d_ws, size_t ws_size,
                              hipStream_t stream) {
  const float* x = (const float*)d_in[0];
  const int* ei = (const int*)d_in[1];
  const float* ea = (const float*)d_in[2];
  const float* l0_lin_w = (const float*)d_in[3];
  const float* l0_lin_b = (const float*)d_in[4];
  const float* l0_w1 = (const float*)d_in[5];
  const float* l0_b1 = (const float*)d_in[6];
  const float* l0_w2 = (const float*)d_in[7];
  const float* l0_b2 = (const float*)d_in[8];
  const float* l0_ln_g = (const float*)d_in[9];
  const float* l0_ln_b = (const float*)d_in[10];
  const float* l0_res_w = (const float*)d_in[11];
  const float* l0_res_b = (const float*)d_in[12];
  const float* dec_w1 = (const float*)d_in[29];
  const float* dec_b1 = (const float*)d_in[30];
  const float* dec_w2 = (const float*)d_in[31];
  const float* dec_b2 = (const float*)d_in[32];
  const float* dec_w3 = (const float*)d_in[33];
  const float* dec_b3 = (const float*)d_in[34];

  float* h_a = (float*)d_ws;                      // NN*64 f32
  float* h_b = h_a + (size_t)NN * 64;             // NN*64 f32
  ushort* hbA = (ushort*)(h_b + (size_t)NN * 64); // NN*64 bf16
  ushort* hbB = hbA + (size_t)NN * 64;            // NN*64 bf16
  int* ipos = (int*)(hbB + (size_t)NN * 64);      // NE
  int* srcp = ipos + NE;                          // NE
  int* dstp = srcp + NE;                          // NE
  float* tmp = (float*)(dstp + NE);               // NE f32 (sorted decoder out)
  int* off = (int*)(tmp + NE);                    // NN+1
  int* cnt = off + (NN + 1);                      // NN
  int* bsum = cnt + NN;                           // 256
  ushort* w1f = (ushort*)(bsum + 256);            // 18432 bf16
  ushort* w2f = w1f + 18432;                      // 2048 bf16
  ushort* eapb = w2f + 2048;                      // NE*8 bf16
  ushort* wmlp = eapb + (size_t)NE * 8;           // 32768 bf16 (l1/l2 MLP w)
  ushort* wmlp0 = wmlp + 32768;                   // 16384 bf16 (l0 MLP w)
  float* tacc = (float*)(wmlp0 + 16384);          // NN*64 f32 (aggregates)

  const int EB = (NE + 255) / 256;                // 3907
  const int SB = (NN + 256) / 256;                // 196
  const int MB = ((NN + 31) / 32 + 1) / 2;        // mlp blocks (2 waves each)

  // ---- CSR build ----
  hipMemsetAsync(cnt, 0, (size_t)NN * sizeof(int), stream);
  hist_kernel<<<EB, 256, 0, stream>>>(ei, cnt);
  scan1_kernel<<<SB, 256, 0, stream>>>(cnt, off, bsum);
  scan2_kernel<<<1, 256, 0, stream>>>(bsum, SB);
  scan3_kernel<<<SB, 256, 0, stream>>>(off, bsum, cnt);
  scatter_kernel<<<EB, 256, 0, stream>>>(ei, ea, off, cnt, ipos, srcp, dstp, eapb);
  prep_mlpw<<<64, 256, 0, stream>>>((const float*)d_in[15], (const float*)d_in[17],
                                    (const float*)d_in[23], (const float*)d_in[25],
                                    wmlp);
  prep_mlp0<<<32, 256, 0, stream>>>(l0_w1, l0_w2, l0_res_w, wmlp0);

  // ---- layer 0 ----
  aggr0_kernel<<<NN / 4, 256, 0, stream>>>(x, tacc, eapb, srcp, off,
                                           l0_lin_w, l0_lin_b);
  mlp0_kernel<<<MB, 128, 0, stream>>>(x, tacc, h_a, hbA, wmlp0,
                                      l0_b1, l0_b2, l0_res_b, l0_ln_g, l0_ln_b);

  // ---- layers 1/2 ----
  aggr_kernel<<<NN / 4, 256, 0, stream>>>(hbA, tacc, eapb, srcp, off,
                                          (const float*)d_in[13],
                                          (const float*)d_in[14]);
  mlp_kernel<<<MB, 128, 0, stream>>>(tacc, h_a, h_b, hbB, wmlp,
                                     (const float*)d_in[16], (const float*)d_in[18],
                                     (const float*)d_in[19], (const float*)d_in[20]);
  aggr_kernel<<<NN / 4, 256, 0, stream>>>(hbB, tacc, eapb, srcp, off,
                                          (const float*)d_in[21],
                                          (const float*)d_in[22]);
  mlp_kernel<<<MB, 128, 0, stream>>>(tacc, h_b, (float*)nullptr, hbA, wmlp + 16384,
                                     (const float*)d_in[24], (const float*)d_in[26],
                                     (const float*)d_in[27], (const float*)d_in[28]);

  // ---- decoder ----
  prep_kernel<<<80, 256, 0, stream>>>(dec_w1, dec_w2, w1f, w2f);
  decoder_kernel<<<8 * BPXD, 128, 0, stream>>>(hbA, srcp, dstp, eapb,
                                               w1f, w2f, dec_b1, dec_b2,
                                               dec_w3, dec_b3, tmp);
  unperm_kernel<<<EB, 256, 0, stream>>>(tmp, ipos, (float*)d_out);
}

// Round 10
// 536.060 us; speedup vs baseline: 1.1951x; 1.1951x over previous
//
#include <hip/hip_runtime.h>

#define NN 50000
#define NE 1000000

constexpr float LN_EPS = 1e-5f;

typedef short bf16x8 __attribute__((ext_vector_type(8)));
typedef float f32x4 __attribute__((ext_vector_type(4)));
typedef uint uvec4 __attribute__((ext_vector_type(4)));
typedef uint uvec2 __attribute__((ext_vector_type(2)));

// hardware RNE f32x2 -> bf16x2 pack (gfx950 v_cvt_pk_bf16_f32; no builtin)
__device__ inline uint cvtpk(float a, float b) {
  uint r;
  asm("v_cvt_pk_bf16_f32 %0, %1, %2" : "=v"(r) : "v"(a), "v"(b));
  return r;
}
__device__ inline ushort cvt1(float a) {
  uint r;
  asm("v_cvt_pk_bf16_f32 %0, %1, %1" : "=v"(r) : "v"(a));
  return (ushort)r;
}
__device__ inline float bflo(uint u) { union { uint x; float f; } v; v.x = u << 16; return v.f; }
__device__ inline float bfhi(uint u) { union { uint x; float f; } v; v.x = u & 0xffff0000u; return v.f; }

// ---------------------------------------------------------------------------
// CSR build: histogram -> exclusive scan -> scatter.
__global__ __launch_bounds__(256) void hist_kernel(const int* __restrict__ ei,
                                                   int* __restrict__ cnt) {
  int e = blockIdx.x * 256 + threadIdx.x;
  if (e < NE) atomicAdd(&cnt[ei[NE + e]], 1);
}

__global__ __launch_bounds__(256) void scan1_kernel(const int* __restrict__ cnt,
                                                    int* __restrict__ off,
                                                    int* __restrict__ bsum) {
  __shared__ int sh[256];
  int t = threadIdx.x;
  int idx = blockIdx.x * 256 + t;
  int v = (idx < NN) ? cnt[idx] : 0;
  sh[t] = v;
  __syncthreads();
  for (int o = 1; o < 256; o <<= 1) {
    int xv = (t >= o) ? sh[t - o] : 0;
    __syncthreads();
    sh[t] += xv;
    __syncthreads();
  }
  if (idx <= NN) off[idx] = sh[t] - v;
  if (t == 255) bsum[blockIdx.x] = sh[255];
}

__global__ __launch_bounds__(256) void scan2_kernel(int* __restrict__ bsum, int nb) {
  __shared__ int sh[256];
  int t = threadIdx.x;
  int v = (t < nb) ? bsum[t] : 0;
  sh[t] = v;
  __syncthreads();
  for (int o = 1; o < 256; o <<= 1) {
    int xv = (t >= o) ? sh[t - o] : 0;
    __syncthreads();
    sh[t] += xv;
    __syncthreads();
  }
  if (t < nb) bsum[t] = sh[t] - v;
}

__global__ __launch_bounds__(256) void scan3_kernel(int* __restrict__ off,
                                                    const int* __restrict__ bsum,
                                                    int* __restrict__ cnt) {
  int idx = blockIdx.x * 256 + threadIdx.x;
  if (idx <= NN) off[idx] += bsum[blockIdx.x];
  if (idx < NN) cnt[idx] = 0;
}

// scatter emits: srcp/dstp (sorted endpoint ids), eapb (dst-sorted bf16 edge
// attrs), ipos (edge -> sorted position inverse map, coalesced by e).
__global__ __launch_bounds__(256) void scatter_kernel(
    const int* __restrict__ ei, const float* __restrict__ ea,
    const int* __restrict__ off, int* __restrict__ cur,
    int* __restrict__ ipos, int* __restrict__ srcp, int* __restrict__ dstp,
    ushort* __restrict__ eapb) {
  int e = blockIdx.x * 256 + threadIdx.x;
  if (e < NE) {
    int d = ei[NE + e];
    int s = ei[e];
    int p = off[d] + atomicAdd(&cur[d], 1);
    ipos[e] = p;
    srcp[p] = s;
    dstp[p] = d;
    const float* eaf = ea + (size_t)e * 8;
    f32x4 e0 = *(const f32x4*)(eaf);
    f32x4 e1 = *(const f32x4*)(eaf + 4);
    uvec4 u;
    u.x = cvtpk(e0.x, e0.y);
    u.y = cvtpk(e0.z, e0.w);
    u.z = cvtpk(e1.x, e1.y);
    u.w = cvtpk(e1.z, e1.w);
    __builtin_nontemporal_store(u, (uvec4*)(eapb + (size_t)p * 8));
  }
}

// unpermute: coalesced write of out, random 4B read of the 4MB tmp table
// (L2-absorbed; random READS are cheap, random writes are not -- R8 lesson).
__global__ __launch_bounds__(256) void unperm_kernel(const float* __restrict__ tmp,
                                                     const int* __restrict__ ipos,
                                                     float* __restrict__ out) {
  int e = blockIdx.x * 256 + threadIdx.x;
  if (e < NE) out[e] = tmp[ipos[e]];
}

// ---------------------------------------------------------------------------
// Layer-0 aggregation (D=16): per-node wave, 4 edges in flight (slot = j>>4),
// writes the f32 16-dim aggregate only. MLP+residual+LN run in mlp0_kernel.
__global__ __launch_bounds__(256) void aggr0_kernel(
    const float* __restrict__ x, float* __restrict__ tout16,
    const ushort* __restrict__ eapb, const int* __restrict__ srcp,
    const int* __restrict__ off,
    const float* __restrict__ lw, const float* __restrict__ lb) {
  int n = blockIdx.x * 4 + (threadIdx.x >> 6);
  int j = threadIdx.x & 63;
  int d = j & 15, slot = j >> 4;
  int start = off[n], end = off[n + 1];
  float lwv[8];
#pragma unroll
  for (int i = 0; i < 8; i++) lwv[i] = lw[i * 16 + d];
  float lbv = lb[d];
  float acc = 0.f;
  for (int base = start; base < end; base += 64) {
    int idx = base + j;
    int sl = (idx < end) ? srcp[idx] : 0;
    int c = min(end - base, 64);
    for (int i0 = 0; i0 < c; i0 += 4) {
      int i = i0 + slot;
      bool valid = i < c;
      int ii = i & 63;
      int s = __shfl(sl, ii);
      int pp = min(base + i0 + slot, NE - 1);
      float ev = bflo((uint)eapb[(size_t)pp * 8 + (d & 7)]);
      float xs = x[(size_t)s * 16 + d];
      float m = lbv + xs;
#pragma unroll
      for (int q = 0; q < 8; q++) m = fmaf(__shfl(ev, slot * 16 + q), lwv[q], m);
      m = fmaxf(m, 0.f);
      acc += valid ? m : 0.f;
    }
  }
  acc += __shfl_xor(acc, 16);
  acc += __shfl_xor(acc, 32);
  if (slot == 0) tout16[(size_t)n * 16 + d] = acc;
}

// ---------------------------------------------------------------------------
// Aggregation for layers 1/2 (D=64): shfl-free edge loop (wave-uniform src
// ids + edge attrs via readfirstlane -> SGPR operands), 8 gathers in flight.
__device__ inline float edge8_msg(const ushort* __restrict__ hinb, int s, int j,
                                  uint ulo, uint uhi, uint vlo, uint vhi,
                                  const float* lwv, float lbv) {
  float hc = bflo((uint)hinb[(size_t)s * 64 + j]);
  float m = lbv + hc;
  m = fmaf(bflo(ulo), lwv[0], m);
  m = fmaf(bfhi(ulo), lwv[1], m);
  m = fmaf(bflo(uhi), lwv[2], m);
  m = fmaf(bfhi(uhi), lwv[3], m);
  m = fmaf(bflo(vlo), lwv[4], m);
  m = fmaf(bfhi(vlo), lwv[5], m);
  m = fmaf(bflo(vhi), lwv[6], m);
  m = fmaf(bfhi(vhi), lwv[7], m);
  return fmaxf(m, 0.f);
}

__global__ __launch_bounds__(256) void aggr_kernel(
    const ushort* __restrict__ hinb, float* __restrict__ tout,
    const ushort* __restrict__ eapb, const int* __restrict__ srcp,
    const int* __restrict__ off,
    const float* __restrict__ lw, const float* __restrict__ lb) {
  int n = blockIdx.x * 4 + (threadIdx.x >> 6);
  int j = threadIdx.x & 63;
  int start = __builtin_amdgcn_readfirstlane(off[n]);
  int end = __builtin_amdgcn_readfirstlane(off[n + 1]);
  float lwv[8];
#pragma unroll
  for (int i = 0; i < 8; i++) lwv[i] = lw[i * 64 + j];
  float lbv = lb[j];
  float acc = 0.f;
  int p = start;
  for (; p + 8 <= end; p += 8) {
    const uvec4* ip = (const uvec4*)(srcp + p);
    uvec4 I0 = __builtin_nontemporal_load(ip + 0);
    uvec4 I1 = __builtin_nontemporal_load(ip + 1);
    int s0 = __builtin_amdgcn_readfirstlane((int)I0.x);
    int s1 = __builtin_amdgcn_readfirstlane((int)I0.y);
    int s2 = __builtin_amdgcn_readfirstlane((int)I0.z);
    int s3 = __builtin_amdgcn_readfirstlane((int)I0.w);
    int s4 = __builtin_amdgcn_readfirstlane((int)I1.x);
    int s5 = __builtin_amdgcn_readfirstlane((int)I1.y);
    int s6 = __builtin_amdgcn_readfirstlane((int)I1.z);
    int s7 = __builtin_amdgcn_readfirstlane((int)I1.w);
    const uvec4* ep = (const uvec4*)(eapb + (size_t)p * 8);
    uint ua[8][4];
#pragma unroll
    for (int i = 0; i < 8; i++) {
      uvec4 E = __builtin_nontemporal_load(ep + i);
      ua[i][0] = __builtin_amdgcn_readfirstlane(E.x);
      ua[i][1] = __builtin_amdgcn_readfirstlane(E.y);
      ua[i][2] = __builtin_amdgcn_readfirstlane(E.z);
      ua[i][3] = __builtin_amdgcn_readfirstlane(E.w);
    }
    acc += edge8_msg(hinb, s0, j, ua[0][0], ua[0][1], ua[0][2], ua[0][3], lwv, lbv);
    acc += edge8_msg(hinb, s1, j, ua[1][0], ua[1][1], ua[1][2], ua[1][3], lwv, lbv);
    acc += edge8_msg(hinb, s2, j, ua[2][0], ua[2][1], ua[2][2], ua[2][3], lwv, lbv);
    acc += edge8_msg(hinb, s3, j, ua[3][0], ua[3][1], ua[3][2], ua[3][3], lwv, lbv);
    acc += edge8_msg(hinb, s4, j, ua[4][0], ua[4][1], ua[4][2], ua[4][3], lwv, lbv);
    acc += edge8_msg(hinb, s5, j, ua[5][0], ua[5][1], ua[5][2], ua[5][3], lwv, lbv);
    acc += edge8_msg(hinb, s6, j, ua[6][0], ua[6][1], ua[6][2], ua[6][3], lwv, lbv);
    acc += edge8_msg(hinb, s7, j, ua[7][0], ua[7][1], ua[7][2], ua[7][3], lwv, lbv);
  }
  for (; p < end; p++) {
    int s = __builtin_amdgcn_readfirstlane(srcp[p]);
    uvec4 E = __builtin_nontemporal_load((const uvec4*)(eapb + (size_t)p * 8));
    uint e0 = __builtin_amdgcn_readfirstlane(E.x);
    uint e1 = __builtin_amdgcn_readfirstlane(E.y);
    uint e2 = __builtin_amdgcn_readfirstlane(E.z);
    uint e3 = __builtin_amdgcn_readfirstlane(E.w);
    acc += edge8_msg(hinb, s, j, e0, e1, e2, e3, lwv, lbv);
  }
  tout[(size_t)n * 64 + j] = acc;
}

// ---------------------------------------------------------------------------
// Prep: dec_w1 (264x64, K zero-padded to 288) and dec_w2 (64x32) into per-lane
// bf16 B-fragments for mfma_f32_16x16x32_bf16.
__global__ __launch_bounds__(256) void prep_kernel(
    const float* __restrict__ w1, const float* __restrict__ w2,
    ushort* __restrict__ w1f, ushort* __restrict__ w2f) {
  int t = blockIdx.x * 256 + threadIdx.x;
  if (t < 18432) {
    int j = t & 7, lane = (t >> 3) & 63, f = t >> 9;
    int k = (f >> 2) * 32 + ((lane >> 4) * 8) + j;
    int n = (f & 3) * 16 + (lane & 15);
    float v = (k < 264) ? w1[k * 64 + n] : 0.f;
    w1f[t] = cvt1(v);
  } else {
    int t2 = t - 18432;
    int j = t2 & 7, lane = (t2 >> 3) & 63, f = t2 >> 9;
    int k = (f >> 1) * 32 + ((lane >> 4) * 8) + j;
    int n = (f & 1) * 16 + (lane & 15);
    w2f[t2] = cvt1(w2[k * 32 + n]);
  }
}

// Prep hi/lo B-fragments for the layer-1/2 MLP weights (each 64x64).
// Output layout per layer (16384 ushorts): [w1h, w1l, w2h, w2l] x 4096.
__global__ __launch_bounds__(256) void prep_mlpw(
    const float* __restrict__ w1a, const float* __restrict__ w2a,
    const float* __restrict__ w1b, const float* __restrict__ w2b,
    ushort* __restrict__ out) {
  int t = blockIdx.x * 256 + threadIdx.x;  // 16384 threads
  int layer = t >> 13, wsel = (t >> 12) & 1, idx = t & 4095;
  const float* w = layer ? (wsel ? w2b : w1b) : (wsel ? w2a : w1a);
  int j = idx & 7, lane = (idx >> 3) & 63, f = idx >> 9;
  int k = (f >> 2) * 32 + ((lane >> 4) * 8) + j;
  int n = (f & 3) * 16 + (lane & 15);
  float v = w[k * 64 + n];
  ushort h = cvt1(v);
  float r = v - bflo((uint)h);
  ushort lo = cvt1(r);
  int base = layer * 16384 + wsel * 8192;
  out[base + idx] = h;
  out[base + 4096 + idx] = lo;
}

// Prep layer-0 MLP B-fragments (hi/lo): B1 = [w1(16x64); 0] (K=32, 4 frags),
// B2 = [0; rw(16x64)] (4 frags), W2 = w2(64x64) (8 frags).
// Layout: [B1h 0][B1l 2048][B2h 4096][B2l 6144][W2h 8192][W2l 12288].
__global__ __launch_bounds__(256) void prep_mlp0(
    const float* __restrict__ w1, const float* __restrict__ w2,
    const float* __restrict__ rw, ushort* __restrict__ out) {
  int t = blockIdx.x * 256 + threadIdx.x;  // 8192 threads
  if (t < 4096) {
    int which = t >> 11, idx = t & 2047;
    int j = idx & 7, lane = (idx >> 3) & 63, f = idx >> 9;
    int k = ((lane >> 4) * 8) + j;
    int n = f * 16 + (lane & 15);
    float v;
    if (which == 0) v = (k < 16) ? w1[k * 64 + n] : 0.f;
    else            v = (k >= 16) ? rw[(k - 16) * 64 + n] : 0.f;
    ushort h = cvt1(v);
    float r = v - bflo((uint)h);
    int base = which * 4096;
    out[base + idx] = h;
    out[base + 2048 + idx] = cvt1(r);
  } else {
    int idx = t - 4096;  // 0..4095
    int j = idx & 7, lane = (idx >> 3) & 63, f = idx >> 9;
    int k = (f >> 2) * 32 + ((lane >> 4) * 8) + j;
    int n = (f & 3) * 16 + (lane & 15);
    float v = w2[k * 64 + n];
    ushort h = cvt1(v);
    float r = v - bflo((uint)h);
    out[8192 + idx] = h;
    out[12288 + idx] = cvt1(r);
  }
}

// ---------------------------------------------------------------------------
// MFMA node-MLP + LayerNorm for layers 1/2. M=32 rows per wave, 2 waves/block.
#define YS2 68

__global__ __launch_bounds__(128) void mlp_kernel(
    const float* __restrict__ tacc, const float* __restrict__ hinf,
    float* __restrict__ houtf, ushort* __restrict__ houtbf,
    const ushort* __restrict__ wf,
    const float* __restrict__ b1, const float* __restrict__ b2,
    const float* __restrict__ lng, const float* __restrict__ lnb) {
  __shared__ float ybuf[2][32 * YS2];
  const int w = threadIdx.x >> 6, l = threadIdx.x & 63;
  const int sub = l & 15, quad = l >> 4;
  const int wid = blockIdx.x * 2 + w;
  const int r0 = wid * 32;
  if (r0 >= NN) return;
  float* Y = ybuf[w];

  const bf16x8* w1h = (const bf16x8*)wf;
  const bf16x8* w1l = (const bf16x8*)(wf + 4096);
  const bf16x8* w2h = (const bf16x8*)(wf + 8192);
  const bf16x8* w2l = (const bf16x8*)(wf + 12288);

  union UF { uvec4 u; bf16x8 v; };

  // stage-1 A fragments (hi/lo) from t = tacc + hinf
  bf16x8 Ahi[2][2], Alo[2][2];
#pragma unroll
  for (int m = 0; m < 2; m++) {
    int row = min(r0 + m * 16 + sub, NN - 1);
    const float* pt = tacc + (size_t)row * 64 + quad * 8;
    const float* ph = hinf + (size_t)row * 64 + quad * 8;
#pragma unroll
    for (int ks = 0; ks < 2; ks++) {
      f32x4 t0 = *(const f32x4*)(pt + ks * 32);
      f32x4 t1 = *(const f32x4*)(pt + ks * 32 + 4);
      f32x4 h0 = *(const f32x4*)(ph + ks * 32);
      f32x4 h1 = *(const f32x4*)(ph + ks * 32 + 4);
      t0 += h0;
      t1 += h1;
      UF uh, ul;
      uh.u.x = cvtpk(t0.x, t0.y);
      uh.u.y = cvtpk(t0.z, t0.w);
      uh.u.z = cvtpk(t1.x, t1.y);
      uh.u.w = cvtpk(t1.z, t1.w);
      ul.u.x = cvtpk(t0.x - bflo(uh.u.x), t0.y - bfhi(uh.u.x));
      ul.u.y = cvtpk(t0.z - bflo(uh.u.y), t0.w - bfhi(uh.u.y));
      ul.u.z = cvtpk(t1.x - bflo(uh.u.z), t1.y - bfhi(uh.u.z));
      ul.u.w = cvtpk(t1.z - bflo(uh.u.w), t1.w - bfhi(uh.u.w));
      Ahi[m][ks] = uh.v;
      Alo[m][ks] = ul.v;
    }
  }

  f32x4 c1[2][4];
#pragma unroll
  for (int m = 0; m < 2; m++)
#pragma unroll
    for (int nb = 0; nb < 4; nb++) c1[m][nb] = (f32x4){0.f, 0.f, 0.f, 0.f};
#pragma unroll
  for (int nb = 0; nb < 4; nb++) {
#pragma unroll
    for (int ks = 0; ks < 2; ks++) {
      bf16x8 bh = w1h[(ks * 4 + nb) * 64 + l];
      bf16x8 bl = w1l[(ks * 4 + nb) * 64 + l];
      c1[0][nb] = __builtin_amdgcn_mfma_f32_16x16x32_bf16(Ahi[0][ks], bh, c1[0][nb], 0, 0, 0);
      c1[1][nb] = __builtin_amdgcn_mfma_f32_16x16x32_bf16(Ahi[1][ks], bh, c1[1][nb], 0, 0, 0);
      c1[0][nb] = __builtin_amdgcn_mfma_f32_16x16x32_bf16(Alo[0][ks], bh, c1[0][nb], 0, 0, 0);
      c1[1][nb] = __builtin_amdgcn_mfma_f32_16x16x32_bf16(Alo[1][ks], bh, c1[1][nb], 0, 0, 0);
      c1[0][nb] = __builtin_amdgcn_mfma_f32_16x16x32_bf16(Ahi[0][ks], bl, c1[0][nb], 0, 0, 0);
      c1[1][nb] = __builtin_amdgcn_mfma_f32_16x16x32_bf16(Ahi[1][ks], bl, c1[1][nb], 0, 0, 0);
    }
  }

  float b1v[4];
#pragma unroll
  for (int nb = 0; nb < 4; nb++) b1v[nb] = b1[nb * 16 + sub];
#pragma unroll
  for (int m = 0; m < 2; m++)
#pragma unroll
    for (int nb = 0; nb < 4; nb++)
#pragma unroll
      for (int r = 0; r < 4; r++)
        Y[(m * 16 + quad * 4 + r) * YS2 + nb * 16 + sub] =
            fmaxf(c1[m][nb][r] + b1v[nb], 0.f);

  bf16x8 Qhi[2][2], Qlo[2][2];
#pragma unroll
  for (int m = 0; m < 2; m++) {
#pragma unroll
    for (int ks = 0; ks < 2; ks++) {
      const float* py = &Y[(m * 16 + sub) * YS2 + ks * 32 + quad * 8];
      f32x4 q0 = *(const f32x4*)py;
      f32x4 q1 = *(const f32x4*)(py + 4);
      UF uh, ul;
      uh.u.x = cvtpk(q0.x, q0.y);
      uh.u.y = cvtpk(q0.z, q0.w);
      uh.u.z = cvtpk(q1.x, q1.y);
      uh.u.w = cvtpk(q1.z, q1.w);
      ul.u.x = cvtpk(q0.x - bflo(uh.u.x), q0.y - bfhi(uh.u.x));
      ul.u.y = cvtpk(q0.z - bflo(uh.u.y), q0.w - bfhi(uh.u.y));
      ul.u.z = cvtpk(q1.x - bflo(uh.u.z), q1.y - bfhi(uh.u.z));
      ul.u.w = cvtpk(q1.z - bflo(uh.u.w), q1.w - bfhi(uh.u.w));
      Qhi[m][ks] = uh.v;
      Qlo[m][ks] = ul.v;
    }
  }

  f32x4 c2[2][4];
#pragma unroll
  for (int m = 0; m < 2; m++)
#pragma unroll
    for (int nb = 0; nb < 4; nb++) c2[m][nb] = (f32x4){0.f, 0.f, 0.f, 0.f};
#pragma unroll
  for (int nb = 0; nb < 4; nb++) {
#pragma unroll
    for (int ks = 0; ks < 2; ks++) {
      bf16x8 bh = w2h[(ks * 4 + nb) * 64 + l];
      bf16x8 bl = w2l[(ks * 4 + nb) * 64 + l];
      c2[0][nb] = __builtin_amdgcn_mfma_f32_16x16x32_bf16(Qhi[0][ks], bh, c2[0][nb], 0, 0, 0);
      c2[1][nb] = __builtin_amdgcn_mfma_f32_16x16x32_bf16(Qhi[1][ks], bh, c2[1][nb], 0, 0, 0);
      c2[0][nb] = __builtin_amdgcn_mfma_f32_16x16x32_bf16(Qlo[0][ks], bh, c2[0][nb], 0, 0, 0);
      c2[1][nb] = __builtin_amdgcn_mfma_f32_16x16x32_bf16(Qlo[1][ks], bh, c2[1][nb], 0, 0, 0);
      c2[0][nb] = __builtin_amdgcn_mfma_f32_16x16x32_bf16(Qhi[0][ks], bl, c2[0][nb], 0, 0, 0);
      c2[1][nb] = __builtin_amdgcn_mfma_f32_16x16x32_bf16(Qhi[1][ks], bl, c2[1][nb], 0, 0, 0);
    }
  }

  float b2v[4], lngv[4], lnbv[4];
#pragma unroll
  for (int nb = 0; nb < 4; nb++) {
    b2v[nb] = b2[nb * 16 + sub];
    lngv[nb] = lng[nb * 16 + sub];
    lnbv[nb] = lnb[nb * 16 + sub];
  }
#pragma unroll
  for (int m = 0; m < 2; m++) {
#pragma unroll
    for (int r = 0; r < 4; r++) {
      int node = r0 + m * 16 + quad * 4 + r;
      int nc = min(node, NN - 1);
      float vp[4];
      float s = 0.f;
#pragma unroll
      for (int nb = 0; nb < 4; nb++) {
        vp[nb] = fmaxf(c2[m][nb][r] + b2v[nb], 0.f) +
                 hinf[(size_t)nc * 64 + nb * 16 + sub];
        s += vp[nb];
      }
      s += __shfl_xor(s, 1);
      s += __shfl_xor(s, 2);
      s += __shfl_xor(s, 4);
      s += __shfl_xor(s, 8);
      float mu = s * (1.f / 64.f);
      float vv = 0.f;
      float dv[4];
#pragma unroll
      for (int nb = 0; nb < 4; nb++) {
        dv[nb] = vp[nb] - mu;
        vv += dv[nb] * dv[nb];
      }
      vv += __shfl_xor(vv, 1);
      vv += __shfl_xor(vv, 2);
      vv += __shfl_xor(vv, 4);
      vv += __shfl_xor(vv, 8);
      float rstd = rsqrtf(vv * (1.f / 64.f) + LN_EPS);
      if (node < NN) {
#pragma unroll
        for (int nb = 0; nb < 4; nb++) {
          float o = dv[nb] * rstd * lngv[nb] + lnbv[nb];
          if (houtf) houtf[(size_t)node * 64 + nb * 16 + sub] = o;
          houtbf[(size_t)node * 64 + nb * 16 + sub] = cvt1(o);
        }
      }
    }
  }
}

// ---------------------------------------------------------------------------
// MFMA node-MLP for layer 0. A = [t | x] (K=32, t = x + aggr16); stage 1
// computes q1 = relu(A@[w1;0]+b1) and res = A@[0;rw] (+rb in epilogue) in one
// fragment pass; stage 2 q1@w2; epilogue LN(relu(.)+res).
__global__ __launch_bounds__(128) void mlp0_kernel(
    const float* __restrict__ x, const float* __restrict__ tacc16,
    float* __restrict__ houtf, ushort* __restrict__ houtbf,
    const ushort* __restrict__ wf,
    const float* __restrict__ b1, const float* __restrict__ b2,
    const float* __restrict__ rb,
    const float* __restrict__ lng, const float* __restrict__ lnb) {
  __shared__ float ybuf[2][32 * YS2];
  const int w = threadIdx.x >> 6, l = threadIdx.x & 63;
  const int sub = l & 15, quad = l >> 4;
  const int wid = blockIdx.x * 2 + w;
  const int r0 = wid * 32;
  if (r0 >= NN) return;
  float* Y = ybuf[w];

  const bf16x8* B1h = (const bf16x8*)wf;
  const bf16x8* B1l = (const bf16x8*)(wf + 2048);
  const bf16x8* B2h = (const bf16x8*)(wf + 4096);
  const bf16x8* B2l = (const bf16x8*)(wf + 6144);
  const bf16x8* W2h = (const bf16x8*)(wf + 8192);
  const bf16x8* W2l = (const bf16x8*)(wf + 12288);

  union UF { uvec4 u; bf16x8 v; };

  // A_cat frags: quads 0,1 -> t = x+aggr (k=0..15); quads 2,3 -> x (k=16..31)
  bf16x8 Ahi[2], Alo[2];
#pragma unroll
  for (int m = 0; m < 2; m++) {
    int row = min(r0 + m * 16 + sub, NN - 1);
    const float* px = x + (size_t)row * 16 + (quad & 1) * 8;
    f32x4 v0 = *(const f32x4*)px;
    f32x4 v1 = *(const f32x4*)(px + 4);
    if (quad < 2) {
      const float* pt = tacc16 + (size_t)row * 16 + (quad & 1) * 8;
      v0 += *(const f32x4*)pt;
      v1 += *(const f32x4*)(pt + 4);
    }
    UF uh, ul;
    uh.u.x = cvtpk(v0.x, v0.y);
    uh.u.y = cvtpk(v0.z, v0.w);
    uh.u.z = cvtpk(v1.x, v1.y);
    uh.u.w = cvtpk(v1.z, v1.w);
    ul.u.x = cvtpk(v0.x - bflo(uh.u.x), v0.y - bfhi(uh.u.x));
    ul.u.y = cvtpk(v0.z - bflo(uh.u.y), v0.w - bfhi(uh.u.y));
    ul.u.z = cvtpk(v1.x - bflo(uh.u.z), v1.y - bfhi(uh.u.z));
    ul.u.w = cvtpk(v1.z - bflo(uh.u.w), v1.w - bfhi(uh.u.w));
    Ahi[m] = uh.v;
    Alo[m] = ul.v;
  }

  f32x4 c1[2][4], cr[2][4];
#pragma unroll
  for (int m = 0; m < 2; m++)
#pragma unroll
    for (int nb = 0; nb < 4; nb++) {
      c1[m][nb] = (f32x4){0.f, 0.f, 0.f, 0.f};
      cr[m][nb] = (f32x4){0.f, 0.f, 0.f, 0.f};
    }
#pragma unroll
  for (int nb = 0; nb < 4; nb++) {
    bf16x8 bh = B1h[nb * 64 + l];
    bf16x8 bl = B1l[nb * 64 + l];
    c1[0][nb] = __builtin_amdgcn_mfma_f32_16x16x32_bf16(Ahi[0], bh, c1[0][nb], 0, 0, 0);
    c1[1][nb] = __builtin_amdgcn_mfma_f32_16x16x32_bf16(Ahi[1], bh, c1[1][nb], 0, 0, 0);
    c1[0][nb] = __builtin_amdgcn_mfma_f32_16x16x32_bf16(Alo[0], bh, c1[0][nb], 0, 0, 0);
    c1[1][nb] = __builtin_amdgcn_mfma_f32_16x16x32_bf16(Alo[1], bh, c1[1][nb], 0, 0, 0);
    c1[0][nb] = __builtin_amdgcn_mfma_f32_16x16x32_bf16(Ahi[0], bl, c1[0][nb], 0, 0, 0);
    c1[1][nb] = __builtin_amdgcn_mfma_f32_16x16x32_bf16(Ahi[1], bl, c1[1][nb], 0, 0, 0);
    bf16x8 rh = B2h[nb * 64 + l];
    bf16x8 rl = B2l[nb * 64 + l];
    cr[0][nb] = __builtin_amdgcn_mfma_f32_16x16x32_bf16(Ahi[0], rh, cr[0][nb], 0, 0, 0);
    cr[1][nb] = __builtin_amdgcn_mfma_f32_16x16x32_bf16(Ahi[1], rh, cr[1][nb], 0, 0, 0);
    cr[0][nb] = __builtin_amdgcn_mfma_f32_16x16x32_bf16(Alo[0], rh, cr[0][nb], 0, 0, 0);
    cr[1][nb] = __builtin_amdgcn_mfma_f32_16x16x32_bf16(Alo[1], rh, cr[1][nb], 0, 0, 0);
    cr[0][nb] = __builtin_amdgcn_mfma_f32_16x16x32_bf16(Ahi[0], rl, cr[0][nb], 0, 0, 0);
    cr[1][nb] = __builtin_amdgcn_mfma_f32_16x16x32_bf16(Ahi[1], rl, cr[1][nb], 0, 0, 0);
  }

  float b1v[4];
#pragma unroll
  for (int nb = 0; nb < 4; nb++) b1v[nb] = b1[nb * 16 + sub];
#pragma unroll
  for (int m = 0; m < 2; m++)
#pragma unroll
    for (int nb = 0; nb < 4; nb++)
#pragma unroll
      for (int r = 0; r < 4; r++)
        Y[(m * 16 + quad * 4 + r) * YS2 + nb * 16 + sub] =
            fmaxf(c1[m][nb][r] + b1v[nb], 0.f);

  bf16x8 Qhi[2][2], Qlo[2][2];
#pragma unroll
  for (int m = 0; m < 2; m++) {
#pragma unroll
    for (int ks = 0; ks < 2; ks++) {
      const float* py = &Y[(m * 16 + sub) * YS2 + ks * 32 + quad * 8];
      f32x4 q0 = *(const f32x4*)py;
      f32x4 q1 = *(const f32x4*)(py + 4);
      UF uh, ul;
      uh.u.x = cvtpk(q0.x, q0.y);
      uh.u.y = cvtpk(q0.z, q0.w);
      uh.u.z = cvtpk(q1.x, q1.y);
      uh.u.w = cvtpk(q1.z, q1.w);
      ul.u.x = cvtpk(q0.x - bflo(uh.u.x), q0.y - bfhi(uh.u.x));
      ul.u.y = cvtpk(q0.z - bflo(uh.u.y), q0.w - bfhi(uh.u.y));
      ul.u.z = cvtpk(q1.x - bflo(uh.u.z), q1.y - bfhi(uh.u.z));
      ul.u.w = cvtpk(q1.z - bflo(uh.u.w), q1.w - bfhi(uh.u.w));
      Qhi[m][ks] = uh.v;
      Qlo[m][ks] = ul.v;
    }
  }

  f32x4 c2[2][4];
#pragma unroll
  for (int m = 0; m < 2; m++)
#pragma unroll
    for (int nb = 0; nb < 4; nb++) c2[m][nb] = (f32x4){0.f, 0.f, 0.f, 0.f};
#pragma unroll
  for (int nb = 0; nb < 4; nb++) {
#pragma unroll
    for (int ks = 0; ks < 2; ks++) {
      bf16x8 bh = W2h[(ks * 4 + nb) * 64 + l];
      bf16x8 bl = W2l[(ks * 4 + nb) * 64 + l];
      c2[0][nb] = __builtin_amdgcn_mfma_f32_16x16x32_bf16(Qhi[0][ks], bh, c2[0][nb], 0, 0, 0);
      c2[1][nb] = __builtin_amdgcn_mfma_f32_16x16x32_bf16(Qhi[1][ks], bh, c2[1][nb], 0, 0, 0);
      c2[0][nb] = __builtin_amdgcn_mfma_f32_16x16x32_bf16(Qlo[0][ks], bh, c2[0][nb], 0, 0, 0);
      c2[1][nb] = __builtin_amdgcn_mfma_f32_16x16x32_bf16(Qlo[1][ks], bh, c2[1][nb], 0, 0, 0);
      c2[0][nb] = __builtin_amdgcn_mfma_f32_16x16x32_bf16(Qhi[0][ks], bl, c2[0][nb], 0, 0, 0);
      c2[1][nb] = __builtin_amdgcn_mfma_f32_16x16x32_bf16(Qhi[1][ks], bl, c2[1][nb], 0, 0, 0);
    }
  }

  float b2v[4], rbv[4], lngv[4], lnbv[4];
#pragma unroll
  for (int nb = 0; nb < 4; nb++) {
    b2v[nb] = b2[nb * 16 + sub];
    rbv[nb] = rb[nb * 16 + sub];
    lngv[nb] = lng[nb * 16 + sub];
    lnbv[nb] = lnb[nb * 16 + sub];
  }
#pragma unroll
  for (int m = 0; m < 2; m++) {
#pragma unroll
    for (int r = 0; r < 4; r++) {
      int node = r0 + m * 16 + quad * 4 + r;
      float vp[4];
      float s = 0.f;
#pragma unroll
      for (int nb = 0; nb < 4; nb++) {
        vp[nb] = fmaxf(c2[m][nb][r] + b2v[nb], 0.f) + cr[m][nb][r] + rbv[nb];
        s += vp[nb];
      }
      s += __shfl_xor(s, 1);
      s += __shfl_xor(s, 2);
      s += __shfl_xor(s, 4);
      s += __shfl_xor(s, 8);
      float mu = s * (1.f / 64.f);
      float vv = 0.f;
      float dv[4];
#pragma unroll
      for (int nb = 0; nb < 4; nb++) {
        dv[nb] = vp[nb] - mu;
        vv += dv[nb] * dv[nb];
      }
      vv += __shfl_xor(vv, 1);
      vv += __shfl_xor(vv, 2);
      vv += __shfl_xor(vv, 4);
      vv += __shfl_xor(vv, 8);
      float rstd = rsqrtf(vv * (1.f / 64.f) + LN_EPS);
      if (node < NN) {
#pragma unroll
        for (int nb = 0; nb < 4; nb++) {
          float o = dv[nb] * rstd * lngv[nb] + lnbv[nb];
          houtf[(size_t)node * 64 + nb * 16 + sub] = o;
          houtbf[(size_t)node * 64 + nb * 16 + sub] = cvt1(o);
        }
      }
    }
  }
}

// ---------------------------------------------------------------------------
// MFMA decoder, CSR-ordered, M=32 per wave. EXACT R5 structure (1 group/wave,
// 128-thread blocks, no multi-group batching -- R6/R9 both spilled) + T5
// s_setprio around the MFMA clusters (independent waves -> scheduler has
// phase diversity to arbitrate; attn-like regime where setprio measured +4-7%).
#define YS 72
#define NBLK 15625
#define BPX 1954

__device__ inline void absmul(bf16x8 a, bf16x8 b, bf16x8& dd, bf16x8& pp) {
  union U { bf16x8 v; uvec4 u; } ua, ub, ud, up;
  ua.v = a; ub.v = b;
#pragma unroll
  for (int i = 0; i < 4; i++) {
    float a0 = bflo(ua.u[i]), a1 = bfhi(ua.u[i]);
    float b0 = bflo(ub.u[i]), b1 = bfhi(ub.u[i]);
    ud.u[i] = cvtpk(fabsf(a0 - b0), fabsf(a1 - b1));
    up.u[i] = cvtpk(a0 * b0, a1 * b1);
  }
  dd = ud.v; pp = up.v;
}

__global__ __launch_bounds__(128, 4) void decoder_kernel(
    const ushort* __restrict__ hb,
    const int* __restrict__ srcp, const int* __restrict__ dstp,
    const ushort* __restrict__ eapb,
    const ushort* __restrict__ w1f, const ushort* __restrict__ w2f,
    const float* __restrict__ b1, const float* __restrict__ b2,
    const float* __restrict__ w3, const float* __restrict__ b3,
    float* __restrict__ tmp) {
  __shared__ ushort ybuf[2][32 * YS];
  const int w = threadIdx.x >> 6, l = threadIdx.x & 63;
  const int sub = l & 15, quad = l >> 4;
  int bb = (blockIdx.x & 7) * BPX + (blockIdx.x >> 3);
  if (bb >= NBLK) return;
  const int g = bb * 2 + w;
  ushort* Y = ybuf[w];

  int s32 = __builtin_nontemporal_load(&srcp[g * 32 + (l & 31)]);
  int d32 = __builtin_nontemporal_load(&dstp[g * 32 + (l & 31)]);

  bf16x8 alo[2], ahi[2], blo[2], bhi[2];
#pragma unroll
  for (int m = 0; m < 2; m++) {
    int sA = __shfl(s32, m * 16 + sub);
    int dA = __shfl(d32, m * 16 + sub);
    const ushort* pa = hb + (size_t)sA * 64 + quad * 8;
    const ushort* pb = hb + (size_t)dA * 64 + quad * 8;
    alo[m] = *(const bf16x8*)pa;
    ahi[m] = *(const bf16x8*)(pa + 32);
    blo[m] = *(const bf16x8*)pb;
    bhi[m] = *(const bf16x8*)(pb + 32);
  }
  bf16x8 eaf0 = (bf16x8){0, 0, 0, 0, 0, 0, 0, 0};
  bf16x8 eaf1 = (bf16x8){0, 0, 0, 0, 0, 0, 0, 0};
  if (quad == 0) {
    eaf0 = *(const bf16x8*)&eapb[((size_t)g * 32 + sub) * 8];
    eaf1 = *(const bf16x8*)&eapb[((size_t)g * 32 + 16 + sub) * 8];
  }

  float b1v[4];
#pragma unroll
  for (int t = 0; t < 4; t++) b1v[t] = b1[t * 16 + sub];
  float b2v0 = b2[sub], b2v1 = b2[16 + sub];
  float w3v0 = w3[sub], w3v1 = w3[16 + sub];
  float b3v = b3[0];

  f32x4 acc[2][4];
#pragma unroll
  for (int m = 0; m < 2; m++)
#pragma unroll
    for (int t = 0; t < 4; t++) acc[m][t] = (f32x4){0.f, 0.f, 0.f, 0.f};

#define MF(sB, f0, f1)                                                        \
  {                                                                           \
    _Pragma("unroll") for (int t = 0; t < 4; t++) {                           \
      bf16x8 bfv = ((const bf16x8*)w1f)[((sB)*4 + t) * 64 + l];               \
      acc[0][t] = __builtin_amdgcn_mfma_f32_16x16x32_bf16(f0, bfv, acc[0][t], \
                                                          0, 0, 0);           \
      acc[1][t] = __builtin_amdgcn_mfma_f32_16x16x32_bf16(f1, bfv, acc[1][t], \
                                                          0, 0, 0);           \
    }                                                                         \
  }

  __builtin_amdgcn_s_setprio(1);
  {
    bf16x8 dlo0, plo0, dlo1, plo1;
    absmul(alo[0], blo[0], dlo0, plo0);
    absmul(alo[1], blo[1], dlo1, plo1);
    MF(0, alo[0], alo[1]);
    MF(2, blo[0], blo[1]);
    MF(4, dlo0, dlo1);
    MF(6, plo0, plo1);
  }
  {
    bf16x8 dhi0, phi0, dhi1, phi1;
    absmul(ahi[0], bhi[0], dhi0, phi0);
    absmul(ahi[1], bhi[1], dhi1, phi1);
    MF(1, ahi[0], ahi[1]);
    MF(3, bhi[0], bhi[1]);
    MF(5, dhi0, dhi1);
    MF(7, phi0, phi1);
  }
  MF(8, eaf0, eaf1);
  __builtin_amdgcn_s_setprio(0);
#undef MF

#pragma unroll
  for (int m = 0; m < 2; m++)
#pragma unroll
    for (int t = 0; t < 4; t++)
#pragma unroll
      for (int r = 0; r < 4; r++)
        Y[(m * 16 + quad * 4 + r) * YS + t * 16 + sub] =
            cvt1(fmaxf(acc[m][t][r] + b1v[t], 0.f));

  bf16x8 w2frag[4];
#pragma unroll
  for (int f = 0; f < 4; f++) w2frag[f] = ((const bf16x8*)w2f)[f * 64 + l];
  f32x4 acc2[2][2];
  __builtin_amdgcn_s_setprio(1);
#pragma unroll
  for (int m = 0; m < 2; m++) {
    acc2[m][0] = (f32x4){0.f, 0.f, 0.f, 0.f};
    acc2[m][1] = (f32x4){0.f, 0.f, 0.f, 0.f};
#pragma unroll
    for (int ks = 0; ks < 2; ks++) {
      bf16x8 ya = *(const bf16x8*)&Y[(m * 16 + sub) * YS + ks * 32 + quad * 8];
      acc2[m][0] = __builtin_amdgcn_mfma_f32_16x16x32_bf16(ya, w2frag[ks * 2 + 0],
                                                           acc2[m][0], 0, 0, 0);
      acc2[m][1] = __builtin_amdgcn_mfma_f32_16x16x32_bf16(ya, w2frag[ks * 2 + 1],
                                                           acc2[m][1], 0, 0, 0);
    }
  }
  __builtin_amdgcn_s_setprio(0);
#pragma unroll
  for (int m = 0; m < 2; m++)
#pragma unroll
    for (int r = 0; r < 4; r++) {
      float o = fmaxf(acc2[m][0][r] + b2v0, 0.f) * w3v0 +
                fmaxf(acc2[m][1][r] + b2v1, 0.f) * w3v1;
      o += __shfl_xor(o, 1);
      o += __shfl_xor(o, 2);
      o += __shfl_xor(o, 4);
      o += __shfl_xor(o, 8);
      if (sub == 0) tmp[g * 32 + m * 16 + quad * 4 + r] = o + b3v;
    }
}

// ---------------------------------------------------------------------------
extern "C" void kernel_launch(void* const* d_in, const int* in_sizes, int n_in,
                              void* d_out, int out_size, void* d_ws, size_t ws_size,
                              hipStream_t stream) {
  const float* x = (const float*)d_in[0];
  const int* ei = (const int*)d_in[1];
  const float* ea = (const float*)d_in[2];
  const float* l0_lin_w = (const float*)d_in[3];
  const float* l0_lin_b = (const float*)d_in[4];
  const float* l0_w1 = (const float*)d_in[5];
  const float* l0_b1 = (const float*)d_in[6];
  const float* l0_w2 = (const float*)d_in[7];
  const float* l0_b2 = (const float*)d_in[8];
  const float* l0_ln_g = (const float*)d_in[9];
  const float* l0_ln_b = (const float*)d_in[10];
  const float* l0_res_w = (const float*)d_in[11];
  const float* l0_res_b = (const float*)d_in[12];
  const float* dec_w1 = (const float*)d_in[29];
  const float* dec_b1 = (const float*)d_in[30];
  const float* dec_w2 = (const float*)d_in[31];
  const float* dec_b2 = (const float*)d_in[32];
  const float* dec_w3 = (const float*)d_in[33];
  const float* dec_b3 = (const float*)d_in[34];

  float* h_a = (float*)d_ws;                      // NN*64 f32
  float* h_b = h_a + (size_t)NN * 64;             // NN*64 f32
  ushort* hbA = (ushort*)(h_b + (size_t)NN * 64); // NN*64 bf16
  ushort* hbB = hbA + (size_t)NN * 64;            // NN*64 bf16
  int* ipos = (int*)(hbB + (size_t)NN * 64);      // NE
  int* srcp = ipos + NE;                          // NE
  int* dstp = srcp + NE;                          // NE
  float* tmp = (float*)(dstp + NE);               // NE f32 (sorted decoder out)
  int* off = (int*)(tmp + NE);                    // NN+1
  int* cnt = off + (NN + 1);                      // NN
  int* bsum = cnt + NN;                           // 256
  ushort* w1f = (ushort*)(bsum + 256);            // 18432 bf16
  ushort* w2f = w1f + 18432;                      // 2048 bf16
  ushort* eapb = w2f + 2048;                      // NE*8 bf16
  ushort* wmlp = eapb + (size_t)NE * 8;           // 32768 bf16 (l1/l2 MLP w)
  ushort* wmlp0 = wmlp + 32768;                   // 16384 bf16 (l0 MLP w)
  float* tacc = (float*)(wmlp0 + 16384);          // NN*64 f32 (aggregates)

  const int EB = (NE + 255) / 256;                // 3907
  const int SB = (NN + 256) / 256;                // 196
  const int MB = ((NN + 31) / 32 + 1) / 2;        // mlp blocks (2 waves each)

  // ---- CSR build ----
  hipMemsetAsync(cnt, 0, (size_t)NN * sizeof(int), stream);
  hist_kernel<<<EB, 256, 0, stream>>>(ei, cnt);
  scan1_kernel<<<SB, 256, 0, stream>>>(cnt, off, bsum);
  scan2_kernel<<<1, 256, 0, stream>>>(bsum, SB);
  scan3_kernel<<<SB, 256, 0, stream>>>(off, bsum, cnt);
  scatter_kernel<<<EB, 256, 0, stream>>>(ei, ea, off, cnt, ipos, srcp, dstp, eapb);
  prep_mlpw<<<64, 256, 0, stream>>>((const float*)d_in[15], (const float*)d_in[17],
                                    (const float*)d_in[23], (const float*)d_in[25],
                                    wmlp);
  prep_mlp0<<<32, 256, 0, stream>>>(l0_w1, l0_w2, l0_res_w, wmlp0);

  // ---- layer 0 ----
  aggr0_kernel<<<NN / 4, 256, 0, stream>>>(x, tacc, eapb, srcp, off,
                                           l0_lin_w, l0_lin_b);
  mlp0_kernel<<<MB, 128, 0, stream>>>(x, tacc, h_a, hbA, wmlp0,
                                      l0_b1, l0_b2, l0_res_b, l0_ln_g, l0_ln_b);

  // ---- layers 1/2 ----
  aggr_kernel<<<NN / 4, 256, 0, stream>>>(hbA, tacc, eapb, srcp, off,
                                          (const float*)d_in[13],
                                          (const float*)d_in[14]);
  mlp_kernel<<<MB, 128, 0, stream>>>(tacc, h_a, h_b, hbB, wmlp,
                                     (const float*)d_in[16], (const float*)d_in[18],
                                     (const float*)d_in[19], (const float*)d_in[20]);
  aggr_kernel<<<NN / 4, 256, 0, stream>>>(hbB, tacc, eapb, srcp, off,
                                          (const float*)d_in[21],
                                          (const float*)d_in[22]);
  mlp_kernel<<<MB, 128, 0, stream>>>(tacc, h_b, (float*)nullptr, hbA, wmlp + 16384,
                                     (const float*)d_in[24], (const float*)d_in[26],
                                     (const float*)d_in[27], (const float*)d_in[28]);

  // ---- decoder ----
  prep_kernel<<<80, 256, 0, stream>>>(dec_w1, dec_w2, w1f, w2f);
  decoder_kernel<<<8 * BPX, 128, 0, stream>>>(hbA, srcp, dstp, eapb,
                                              w1f, w2f, dec_b1, dec_b2,
                                              dec_w3, dec_b3, tmp);
  unperm_kernel<<<EB, 256, 0, stream>>>(tmp, ipos, (float*)d_out);
}